// Round 1
// baseline (763.053 us; speedup 1.0000x reference)
//
#include <hip/hip_runtime.h>
#include <hip/hip_bf16.h>

// Transformer block fwd (B=2,T=2048,C=1024,H=16,D=64,HID=4096), bf16 MFMA compute.
// Round 1: correctness-first. Reg-staged LDS GEMM (no exotic builtins), flash attention.

#define B_ 2
#define T_ 2048
#define C_ 1024
#define H_ 16
#define D_ 64
#define HID_ 4096
#define M_ 4096  // B*T

typedef __bf16 bf16x8 __attribute__((ext_vector_type(8)));
typedef float f32x4 __attribute__((ext_vector_type(4)));
using bf16 = __hip_bfloat16;

static __device__ __forceinline__ f32x4 mfma16(bf16x8 a, bf16x8 b, f32x4 c) {
  return __builtin_amdgcn_mfma_f32_16x16x32_bf16(a, b, c, 0, 0, 0);
}

// ---- weight convert + transpose: in f32 [K][N] -> out bf16 [N][K] ----
__global__ __launch_bounds__(256) void cvt_transpose(const float* __restrict__ in,
                                                     bf16* __restrict__ out, int K, int N) {
  __shared__ float tile[32][33];
  int tid = threadIdx.x, tx = tid & 31, ty = tid >> 5;
  int n0 = blockIdx.x * 32, k0 = blockIdx.y * 32;
#pragma unroll
  for (int i = 0; i < 4; ++i) {
    int r = ty + i * 8;
    tile[r][tx] = in[(size_t)(k0 + r) * N + n0 + tx];
  }
  __syncthreads();
#pragma unroll
  for (int i = 0; i < 4; ++i) {
    int r = ty + i * 8;
    out[(size_t)(n0 + r) * K + k0 + tx] = __float2bfloat16(tile[tx][r]);
  }
}

// ---- RMSNorm: x f32 [rows][1024] -> out bf16 ----
__global__ __launch_bounds__(256) void rmsnorm_kernel(const float* __restrict__ x,
                                                      const float* __restrict__ w,
                                                      bf16* __restrict__ out) {
  int row = blockIdx.x, tid = threadIdx.x;
  float4 v = ((const float4*)(x + (size_t)row * C_))[tid];
  float ss = v.x * v.x + v.y * v.y + v.z * v.z + v.w * v.w;
#pragma unroll
  for (int d = 1; d < 64; d <<= 1) ss += __shfl_xor(ss, d);
  __shared__ float wsum[4];
  if ((tid & 63) == 0) wsum[tid >> 6] = ss;
  __syncthreads();
  float tot = wsum[0] + wsum[1] + wsum[2] + wsum[3];
  float r = rsqrtf(tot * (1.0f / C_) + 1e-5f);
  float4 wv = ((const float4*)w)[tid];
  bf16* o = out + (size_t)row * C_ + tid * 4;
  o[0] = __float2bfloat16(v.x * wv.x * r);
  o[1] = __float2bfloat16(v.y * wv.y * r);
  o[2] = __float2bfloat16(v.z * wv.z * r);
  o[3] = __float2bfloat16(v.w * wv.w * r);
}

// ---- GEMM: C[M,N] = A[M,K] @ Bt[N,K]^T + bias, 128x128 tile, BK=64, 4 waves ----
// EPI 0: QKV scatter (bf16 to (B,H,T,D); optional f32 dup)   EPI 1: f32 out = acc+bias+res
// EPI 2: bf16 out = gelu(acc+bias)
template <int EPI>
__global__ __launch_bounds__(256) void gemm_kernel(
    const bf16* __restrict__ A, const bf16* __restrict__ Bt, const float* __restrict__ bias,
    bf16* __restrict__ bfout, float* __restrict__ fout, const float* __restrict__ res,
    int M, int N, int K) {
  constexpr int LDT = 72;  // 64 + 8 pad elems; row stride 144B (16B aligned, 2-way banks)
  __shared__ bf16 Al[128 * LDT];
  __shared__ bf16 Bl[128 * LDT];
  int tid = threadIdx.x, w = tid >> 6, l = tid & 63;
  int g = l >> 4, c = l & 15;
  int m0 = blockIdx.y * 128, n0 = blockIdx.x * 128;
  int wm = (w >> 1) * 64, wn = (w & 1) * 64;
  int KT = K >> 6;

  uint4 ra[4], rb[4];
  auto fetch = [&](int kt) {
#pragma unroll
    for (int i = 0; i < 4; ++i) {
      int cc = tid + i * 256;
      int row = cc >> 3, k8 = cc & 7;
      ra[i] = *(const uint4*)&A[(size_t)(m0 + row) * K + kt * 64 + k8 * 8];
      rb[i] = *(const uint4*)&Bt[(size_t)(n0 + row) * K + kt * 64 + k8 * 8];
    }
  };

  f32x4 acc[4][4] = {};
  fetch(0);
  for (int kt = 0; kt < KT; ++kt) {
#pragma unroll
    for (int i = 0; i < 4; ++i) {
      int cc = tid + i * 256;
      int row = cc >> 3, k8 = cc & 7;
      *(uint4*)&Al[row * LDT + k8 * 8] = ra[i];
      *(uint4*)&Bl[row * LDT + k8 * 8] = rb[i];
    }
    __syncthreads();
    if (kt + 1 < KT) fetch(kt + 1);  // issue next-tile loads; latency hides under MFMA
#pragma unroll
    for (int ch = 0; ch < 2; ++ch) {
      bf16x8 af[4], bfr[4];
#pragma unroll
      for (int f = 0; f < 4; ++f)
        af[f] = *(const bf16x8*)&Al[(wm + f * 16 + c) * LDT + ch * 32 + g * 8];
#pragma unroll
      for (int f = 0; f < 4; ++f)
        bfr[f] = *(const bf16x8*)&Bl[(wn + f * 16 + c) * LDT + ch * 32 + g * 8];
#pragma unroll
      for (int mf = 0; mf < 4; ++mf)
#pragma unroll
        for (int nf = 0; nf < 4; ++nf) acc[mf][nf] = mfma16(af[mf], bfr[nf], acc[mf][nf]);
    }
    __syncthreads();
  }

#pragma unroll
  for (int mf = 0; mf < 4; ++mf) {
#pragma unroll
    for (int nf = 0; nf < 4; ++nf) {
      int gn = n0 + wn + nf * 16 + c;
      float bv = bias[gn];
#pragma unroll
      for (int r = 0; r < 4; ++r) {
        int gm = m0 + wm + mf * 16 + g * 4 + r;
        float v = acc[mf][nf][r] + bv;
        if (EPI == 0) {
          int b_ = gm >> 11, t = gm & 2047, hh = gn >> 6, d = gn & 63;
          size_t idx = ((size_t)(b_ * H_ + hh) * T_ + t) * D_ + d;
          bfout[idx] = __float2bfloat16(v);
          if (fout) fout[idx] = v;
        } else if (EPI == 1) {
          size_t idx = (size_t)gm * N + gn;
          fout[idx] = v + res[idx];
        } else {
          size_t idx = (size_t)gm * N + gn;
          float gl = 0.5f * v * (1.0f + erff(v * 0.70710678118f));
          bfout[idx] = __float2bfloat16(gl);
        }
      }
    }
  }
}

// ---- Flash attention (causal): Q,K,V bf16 (B,H,T,D) -> ctx bf16 (B,T,C) ----
__global__ __launch_bounds__(256) void attn_kernel(const bf16* __restrict__ Q,
                                                   const bf16* __restrict__ Kb,
                                                   const bf16* __restrict__ Vb,
                                                   bf16* __restrict__ ctx) {
  constexpr int LDV = 68;  // 64+4 pad (8B-aligned rows, breaks worst bank pattern)
  constexpr int LDP = 72;  // 64+8 pad (16B-aligned rows)
  __shared__ bf16 Vl[64 * LDV];
  __shared__ bf16 Pl[4][16 * LDP];
  int tid = threadIdx.x, w = tid >> 6, l = tid & 63, g = l >> 4, c = l & 15;
  int qt = blockIdx.x, bh = blockIdx.y;
  int qbase = qt * 64 + w * 16;
  const bf16* Qh = Q + (size_t)bh * T_ * D_;
  const bf16* Kh = Kb + (size_t)bh * T_ * D_;
  const bf16* Vh = Vb + (size_t)bh * T_ * D_;

  bf16x8 aq[2];
#pragma unroll
  for (int ch = 0; ch < 2; ++ch)
    aq[ch] = *(const bf16x8*)&Qh[(size_t)(qbase + c) * D_ + ch * 32 + g * 8];

  f32x4 o[4] = {};
  float mrun[4], lrun[4];
#pragma unroll
  for (int r = 0; r < 4; ++r) { mrun[r] = -1e30f; lrun[r] = 0.f; }

  for (int kt = 0; kt <= qt; ++kt) {
    int kv0 = kt * 64;
    // stage V tile [64][64] -> LDS (coalesced 8B granules)
#pragma unroll
    for (int i = 0; i < 4; ++i) {
      int gi = tid + i * 256;
      int row = gi >> 4, o4 = gi & 15;
      *(uint2*)&Vl[row * LDV + o4 * 4] = *(const uint2*)&Vh[(size_t)(kv0 + row) * D_ + o4 * 4];
    }
    __syncthreads();

    // S = Q K^T * scale  (4 kv-blocks of 16)
    f32x4 sf[4];
#pragma unroll
    for (int kb = 0; kb < 4; ++kb) {
      bf16x8 bk0 = *(const bf16x8*)&Kh[(size_t)(kv0 + kb * 16 + c) * D_ + g * 8];
      bf16x8 bk1 = *(const bf16x8*)&Kh[(size_t)(kv0 + kb * 16 + c) * D_ + 32 + g * 8];
      f32x4 t = {};
      t = mfma16(aq[0], bk0, t);
      t = mfma16(aq[1], bk1, t);
      sf[kb] = t;
    }
    float s[4][4];
#pragma unroll
    for (int kb = 0; kb < 4; ++kb)
#pragma unroll
      for (int r = 0; r < 4; ++r) s[kb][r] = sf[kb][r] * 0.125f;
    if (kt == qt) {
#pragma unroll
      for (int kb = 0; kb < 4; ++kb)
#pragma unroll
        for (int r = 0; r < 4; ++r) {
          int qi = qbase + g * 4 + r;
          int kv = kv0 + kb * 16 + c;
          if (kv > qi) s[kb][r] = -1e30f;
        }
    }
    // online softmax (row r lives on 16 lanes sharing l>>4)
    float mnew[4], alpha[4];
#pragma unroll
    for (int r = 0; r < 4; ++r) {
      float tm = fmaxf(fmaxf(s[0][r], s[1][r]), fmaxf(s[2][r], s[3][r]));
#pragma unroll
      for (int d = 1; d < 16; d <<= 1) tm = fmaxf(tm, __shfl_xor(tm, d));
      mnew[r] = fmaxf(mrun[r], tm);
      alpha[r] = __expf(mrun[r] - mnew[r]);
      mrun[r] = mnew[r];
    }
#pragma unroll
    for (int r = 0; r < 4; ++r) {
      float asum = 0.f;
#pragma unroll
      for (int kb = 0; kb < 4; ++kb) {
        float p = __expf(s[kb][r] - mnew[r]);
        s[kb][r] = p;
        asum += p;
      }
#pragma unroll
      for (int d = 1; d < 16; d <<= 1) asum += __shfl_xor(asum, d);
      lrun[r] = lrun[r] * alpha[r] + asum;
    }
#pragma unroll
    for (int db = 0; db < 4; ++db)
#pragma unroll
      for (int r = 0; r < 4; ++r) o[db][r] *= alpha[r];

    // P -> LDS (C-layout) -> A-frag layout
#pragma unroll
    for (int kb = 0; kb < 4; ++kb)
#pragma unroll
      for (int r = 0; r < 4; ++r)
        Pl[w][(g * 4 + r) * LDP + kb * 16 + c] = __float2bfloat16(s[kb][r]);
    asm volatile("s_waitcnt lgkmcnt(0)" ::: "memory");
    bf16x8 pa[2];
#pragma unroll
    for (int ch = 0; ch < 2; ++ch)
      pa[ch] = *(const bf16x8*)&Pl[w][c * LDP + ch * 32 + g * 8];

    const unsigned short* Vs = (const unsigned short*)Vl;
#pragma unroll
    for (int db = 0; db < 4; ++db) {
#pragma unroll
      for (int ch = 0; ch < 2; ++ch) {
        union { unsigned short u[8]; bf16x8 v; } bv;
#pragma unroll
        for (int j = 0; j < 8; ++j) bv.u[j] = Vs[(ch * 32 + g * 8 + j) * LDV + db * 16 + c];
        o[db] = mfma16(pa[ch], bv.v, o[db]);
      }
    }
    __syncthreads();
  }

  int b_ = bh >> 4, hh = bh & 15;
#pragma unroll
  for (int r = 0; r < 4; ++r) {
    float inv = 1.0f / lrun[r];
#pragma unroll
    for (int db = 0; db < 4; ++db)
      ctx[(size_t)(b_ * T_ + qbase + g * 4 + r) * C_ + hh * D_ + db * 16 + c] =
          __float2bfloat16(o[db][r] * inv);
  }
}

extern "C" void kernel_launch(void* const* d_in, const int* in_sizes, int n_in, void* d_out,
                              int out_size, void* d_ws, size_t ws_size, hipStream_t stream) {
  const float* x = (const float*)d_in[0];
  const float* anw = (const float*)d_in[2];
  const float* mnw = (const float*)d_in[3];
  const float* q_w = (const float*)d_in[4];
  const float* q_b = (const float*)d_in[5];
  const float* k_w = (const float*)d_in[6];
  const float* k_b = (const float*)d_in[7];
  const float* v_w = (const float*)d_in[8];
  const float* v_b = (const float*)d_in[9];
  const float* o_w = (const float*)d_in[10];
  const float* o_b = (const float*)d_in[11];
  const float* w1 = (const float*)d_in[12];
  const float* b1 = (const float*)d_in[13];
  const float* w2 = (const float*)d_in[14];
  const float* b2 = (const float*)d_in[15];
  float* out = (float*)d_out;
  char* ws = (char*)d_ws;

  // ws layout (80 MB total, with reuse)
  bf16* qwT = (bf16*)(ws + 0);          // 2 MB
  bf16* kwT = (bf16*)(ws + 2097152);
  bf16* vwT = (bf16*)(ws + 4194304);
  bf16* owT = (bf16*)(ws + 6291456);
  bf16* w1T = (bf16*)(ws + 8388608);    // 8 MB
  bf16* w2T = (bf16*)(ws + 16777216);   // 8 MB
  bf16* h = (bf16*)(ws + 25165824);     // 8 MB
  bf16* qb = (bf16*)(ws + 33554432);    // 8 MB
  bf16* kb = (bf16*)(ws + 41943040);    // 8 MB
  bf16* vb = (bf16*)(ws + 50331648);    // 8 MB
  bf16* ctx = (bf16*)(ws + 58720256);   // 8 MB
  float* x2 = (float*)(ws + 67108864);  // 16 MB -> ends 83886080
  bf16* m = h;                          // reuse (h dead after QKV gemms)
  bf16* hid = qb;                       // reuse qb..ctx span = 32 MB (dead after o-proj)
  float* kout = out + 4194304;
  float* vout = out + 8388608;

  cvt_transpose<<<dim3(32, 32), 256, 0, stream>>>(q_w, qwT, 1024, 1024);
  cvt_transpose<<<dim3(32, 32), 256, 0, stream>>>(k_w, kwT, 1024, 1024);
  cvt_transpose<<<dim3(32, 32), 256, 0, stream>>>(v_w, vwT, 1024, 1024);
  cvt_transpose<<<dim3(32, 32), 256, 0, stream>>>(o_w, owT, 1024, 1024);
  cvt_transpose<<<dim3(128, 32), 256, 0, stream>>>(w1, w1T, 1024, 4096);
  cvt_transpose<<<dim3(32, 128), 256, 0, stream>>>(w2, w2T, 4096, 1024);

  rmsnorm_kernel<<<4096, 256, 0, stream>>>(x, anw, h);

  gemm_kernel<0><<<dim3(8, 32), 256, 0, stream>>>(h, qwT, q_b, qb, nullptr, nullptr, 4096, 1024, 1024);
  gemm_kernel<0><<<dim3(8, 32), 256, 0, stream>>>(h, kwT, k_b, kb, kout, nullptr, 4096, 1024, 1024);
  gemm_kernel<0><<<dim3(8, 32), 256, 0, stream>>>(h, vwT, v_b, vb, vout, nullptr, 4096, 1024, 1024);

  attn_kernel<<<dim3(32, 32), 256, 0, stream>>>(qb, kb, vb, ctx);

  gemm_kernel<1><<<dim3(8, 32), 256, 0, stream>>>(ctx, owT, o_b, nullptr, x2, x, 4096, 1024, 1024);

  rmsnorm_kernel<<<4096, 256, 0, stream>>>(x2, mnw, m);

  gemm_kernel<2><<<dim3(32, 32), 256, 0, stream>>>(m, w1T, b1, hid, nullptr, nullptr, 4096, 4096, 1024);
  gemm_kernel<1><<<dim3(8, 32), 256, 0, stream>>>(hid, w2T, b2, nullptr, out, x2, 4096, 1024, 4096);
}

// Round 2
// 427.434 us; speedup vs baseline: 1.7852x; 1.7852x over previous
//
#include <hip/hip_runtime.h>
#include <hip/hip_bf16.h>

// Transformer block fwd (B=2,T=2048,C=1024,H=16,D=64,HID=4096), bf16 MFMA compute.
// Round 2: global_load_lds GEMM staging (m97 structure), fused QKV GEMM,
//          attention with V^T LDS staging (vector ds_read_b128 B-fragments).

#define B_ 2
#define T_ 2048
#define C_ 1024
#define H_ 16
#define D_ 64
#define HID_ 4096
#define M_ 4096  // B*T

typedef __bf16 bf16x8 __attribute__((ext_vector_type(8)));
typedef unsigned short ushort8 __attribute__((ext_vector_type(8)));
typedef float f32x4 __attribute__((ext_vector_type(4)));
using bf16 = __hip_bfloat16;

static __device__ __forceinline__ f32x4 mfma16(bf16x8 a, bf16x8 b, f32x4 c) {
  return __builtin_amdgcn_mfma_f32_16x16x32_bf16(a, b, c, 0, 0, 0);
}

// async global->LDS, 16B per lane; LDS dest = wave-uniform base + lane*16
static __device__ __forceinline__ void gload16(const bf16* g, bf16* l) {
  __builtin_amdgcn_global_load_lds(
      (const __attribute__((address_space(1))) unsigned int*)g,
      (__attribute__((address_space(3))) unsigned int*)l, 16, 0, 0);
}

// ---- weight convert + transpose: in f32 [K][N] -> out bf16 [N][K] ----
__global__ __launch_bounds__(256) void cvt_transpose(const float* __restrict__ in,
                                                     bf16* __restrict__ out, int K, int N) {
  __shared__ float tile[32][33];
  int tid = threadIdx.x, tx = tid & 31, ty = tid >> 5;
  int n0 = blockIdx.x * 32, k0 = blockIdx.y * 32;
#pragma unroll
  for (int i = 0; i < 4; ++i) {
    int r = ty + i * 8;
    tile[r][tx] = in[(size_t)(k0 + r) * N + n0 + tx];
  }
  __syncthreads();
#pragma unroll
  for (int i = 0; i < 4; ++i) {
    int r = ty + i * 8;
    out[(size_t)(n0 + r) * K + k0 + tx] = __float2bfloat16(tile[tx][r]);
  }
}

// ---- pack q/k/v bias into one 3072 vector ----
__global__ __launch_bounds__(256) void pack_bias(const float* __restrict__ q,
                                                 const float* __restrict__ k,
                                                 const float* __restrict__ v,
                                                 float* __restrict__ o) {
  int i = blockIdx.x * 256 + threadIdx.x;
  o[i] = i < 1024 ? q[i] : (i < 2048 ? k[i - 1024] : v[i - 2048]);
}

// ---- RMSNorm: x f32 [rows][1024] -> out bf16 ----
__global__ __launch_bounds__(256) void rmsnorm_kernel(const float* __restrict__ x,
                                                      const float* __restrict__ w,
                                                      bf16* __restrict__ out) {
  int row = blockIdx.x, tid = threadIdx.x;
  float4 v = ((const float4*)(x + (size_t)row * C_))[tid];
  float ss = v.x * v.x + v.y * v.y + v.z * v.z + v.w * v.w;
#pragma unroll
  for (int d = 1; d < 64; d <<= 1) ss += __shfl_xor(ss, d);
  __shared__ float wsum[4];
  if ((tid & 63) == 0) wsum[tid >> 6] = ss;
  __syncthreads();
  float tot = wsum[0] + wsum[1] + wsum[2] + wsum[3];
  float r = rsqrtf(tot * (1.0f / C_) + 1e-5f);
  float4 wv = ((const float4*)w)[tid];
  bf16* o = out + (size_t)row * C_ + tid * 4;
  o[0] = __float2bfloat16(v.x * wv.x * r);
  o[1] = __float2bfloat16(v.y * wv.y * r);
  o[2] = __float2bfloat16(v.z * wv.z * r);
  o[3] = __float2bfloat16(v.w * wv.w * r);
}

// ---- GEMM: C[M,N] = A[M,K] @ Bt[N,K]^T + bias. 128x128 tile, BK=64, 4 waves.
// m97 structure: linear LDS [128][64], global_load_lds width-16 staging.
// EPI 0: fused-QKV scatter (bf16 (B,H,T,D) x3; f32 dup for k,v)
// EPI 1: f32 out = acc + bias + res
// EPI 2: bf16 out = gelu(acc + bias)
template <int EPI>
__global__ __launch_bounds__(256) void gemm_kernel(
    const bf16* __restrict__ A, const bf16* __restrict__ Bt, const float* __restrict__ bias,
    bf16* __restrict__ bfout, float* __restrict__ fout, const float* __restrict__ res,
    int M, int N, int K) {
  __shared__ bf16 Al[128 * 64];
  __shared__ bf16 Bl[128 * 64];
  int tid = threadIdx.x, w = tid >> 6, l = tid & 63;
  int g = l >> 4, c = l & 15;
  int m0 = blockIdx.y * 128, n0 = blockIdx.x * 128;
  int wm = (w >> 1) * 64, wn = (w & 1) * 64;
  int KT = K >> 6;
  int lrow = l >> 3, lcol = (l & 7) * 8;

  const bf16* gA = A + (size_t)(m0 + w * 32 + lrow) * K + lcol;
  const bf16* gB = Bt + (size_t)(n0 + w * 32 + lrow) * K + lcol;

  f32x4 acc[4][4] = {};
  for (int kt = 0; kt < KT; ++kt) {
#pragma unroll
    for (int i = 0; i < 4; ++i) {
      gload16(gA + (size_t)i * 8 * K + kt * 64, Al + (w * 4 + i) * 512);
      gload16(gB + (size_t)i * 8 * K + kt * 64, Bl + (w * 4 + i) * 512);
    }
    __syncthreads();
#pragma unroll
    for (int ch = 0; ch < 2; ++ch) {
      bf16x8 af[4], bfr[4];
#pragma unroll
      for (int f = 0; f < 4; ++f)
        af[f] = *(const bf16x8*)&Al[(wm + f * 16 + c) * 64 + ch * 32 + g * 8];
#pragma unroll
      for (int f = 0; f < 4; ++f)
        bfr[f] = *(const bf16x8*)&Bl[(wn + f * 16 + c) * 64 + ch * 32 + g * 8];
#pragma unroll
      for (int mf = 0; mf < 4; ++mf)
#pragma unroll
        for (int nf = 0; nf < 4; ++nf) acc[mf][nf] = mfma16(af[mf], bfr[nf], acc[mf][nf]);
    }
    __syncthreads();
  }

#pragma unroll
  for (int mf = 0; mf < 4; ++mf) {
#pragma unroll
    for (int nf = 0; nf < 4; ++nf) {
      int gn = n0 + wn + nf * 16 + c;
      float bv = bias[gn];
#pragma unroll
      for (int r = 0; r < 4; ++r) {
        int gm = m0 + wm + mf * 16 + g * 4 + r;
        float v = acc[mf][nf][r] + bv;
        if (EPI == 0) {
          int part = gn >> 10, wi = gn & 1023, hh = wi >> 6, d = wi & 63;
          int b_ = gm >> 11, t = gm & 2047;
          size_t idx = ((size_t)(b_ * H_ + hh) * T_ + t) * D_ + d;
          bfout[(size_t)part * 4194304 + idx] = __float2bfloat16(v);
          if (part) fout[(size_t)part * 4194304 + idx] = v;
        } else if (EPI == 1) {
          size_t idx = (size_t)gm * N + gn;
          fout[idx] = v + res[idx];
        } else {
          size_t idx = (size_t)gm * N + gn;
          float gl = 0.5f * v * (1.0f + erff(v * 0.70710678118f));
          bfout[idx] = __float2bfloat16(gl);
        }
      }
    }
  }
}

// ---- Flash attention (causal): Q,K,V bf16 (B,H,T,D) -> ctx bf16 (B,T,C) ----
// V staged TRANSPOSED in LDS (Vt[d][k]) so PV B-fragments are single ds_read_b128.
__global__ __launch_bounds__(256) void attn_kernel(const bf16* __restrict__ Q,
                                                   const bf16* __restrict__ Kb,
                                                   const bf16* __restrict__ Vb,
                                                   bf16* __restrict__ ctx) {
  constexpr int LDVT = 72;  // row stride 144B: lanes c=0..15 rotate 4 banks/step, 2-way free
  constexpr int LDP = 72;
  __shared__ unsigned short Vt[2][64 * LDVT];  // [d][k], double-buffered
  __shared__ bf16 Pl[4][16 * LDP];
  int tid = threadIdx.x, w = tid >> 6, l = tid & 63, g = l >> 4, c = l & 15;
  int qt = blockIdx.x, bh = blockIdx.y;
  int qbase = qt * 64 + w * 16;
  const bf16* Qh = Q + (size_t)bh * T_ * D_;
  const bf16* Kh = Kb + (size_t)bh * T_ * D_;
  const bf16* Vh = Vb + (size_t)bh * T_ * D_;

  bf16x8 aq[2];
#pragma unroll
  for (int ch = 0; ch < 2; ++ch)
    aq[ch] = *(const bf16x8*)&Qh[(size_t)(qbase + c) * D_ + ch * 32 + g * 8];

  f32x4 o[4] = {};
  float mrun[4], lrun[4];
#pragma unroll
  for (int r = 0; r < 4; ++r) { mrun[r] = -1e30f; lrun[r] = 0.f; }

  auto stageV = [&](int kt, int buf) {
#pragma unroll
    for (int i = 0; i < 2; ++i) {
      int gi = tid + i * 256;
      int row = gi >> 3, dblk = gi & 7;  // row = k index, dblk*8 = d start
      ushort8 pk = *(const ushort8*)&Vh[(size_t)(kt * 64 + row) * D_ + dblk * 8];
#pragma unroll
      for (int j = 0; j < 8; ++j) Vt[buf][(dblk * 8 + j) * LDVT + row] = pk[j];
    }
  };

  stageV(0, 0);
  for (int kt = 0; kt <= qt; ++kt) {
    int cur = kt & 1;
    int kv0 = kt * 64;
    __syncthreads();  // staged Vt[cur] ready; prev-iter reads of Vt[cur^1] done
    if (kt < qt) stageV(kt + 1, cur ^ 1);

    // S = Q K^T * scale  (K fragments straight from global; tile is L2-hot)
    f32x4 sf[4];
#pragma unroll
    for (int kb = 0; kb < 4; ++kb) {
      bf16x8 bk0 = *(const bf16x8*)&Kh[(size_t)(kv0 + kb * 16 + c) * D_ + g * 8];
      bf16x8 bk1 = *(const bf16x8*)&Kh[(size_t)(kv0 + kb * 16 + c) * D_ + 32 + g * 8];
      f32x4 t = {};
      t = mfma16(aq[0], bk0, t);
      t = mfma16(aq[1], bk1, t);
      sf[kb] = t;
    }
    float s[4][4];
#pragma unroll
    for (int kb = 0; kb < 4; ++kb)
#pragma unroll
      for (int r = 0; r < 4; ++r) s[kb][r] = sf[kb][r] * 0.125f;
    if (kt == qt) {
#pragma unroll
      for (int kb = 0; kb < 4; ++kb)
#pragma unroll
        for (int r = 0; r < 4; ++r) {
          int qi = qbase + g * 4 + r;
          int kv = kv0 + kb * 16 + c;
          if (kv > qi) s[kb][r] = -1e30f;
        }
    }
    // online softmax (row q = g*4+r lives on the 16 lanes sharing g)
    float mnew[4], alpha[4];
#pragma unroll
    for (int r = 0; r < 4; ++r) {
      float tm = fmaxf(fmaxf(s[0][r], s[1][r]), fmaxf(s[2][r], s[3][r]));
#pragma unroll
      for (int d = 1; d < 16; d <<= 1) tm = fmaxf(tm, __shfl_xor(tm, d));
      mnew[r] = fmaxf(mrun[r], tm);
      alpha[r] = __expf(mrun[r] - mnew[r]);
      mrun[r] = mnew[r];
    }
#pragma unroll
    for (int r = 0; r < 4; ++r) {
      float asum = 0.f;
#pragma unroll
      for (int kb = 0; kb < 4; ++kb) {
        float p = __expf(s[kb][r] - mnew[r]);
        s[kb][r] = p;
        asum += p;
      }
#pragma unroll
      for (int d = 1; d < 16; d <<= 1) asum += __shfl_xor(asum, d);
      lrun[r] = lrun[r] * alpha[r] + asum;
    }
#pragma unroll
    for (int db = 0; db < 4; ++db)
#pragma unroll
      for (int r = 0; r < 4; ++r) o[db][r] *= alpha[r];

    // P (C-layout) -> per-wave LDS -> A-fragment layout
#pragma unroll
    for (int kb = 0; kb < 4; ++kb)
#pragma unroll
      for (int r = 0; r < 4; ++r)
        Pl[w][(g * 4 + r) * LDP + kb * 16 + c] = __float2bfloat16(s[kb][r]);
    bf16x8 pa[2];
#pragma unroll
    for (int ch = 0; ch < 2; ++ch)
      pa[ch] = *(const bf16x8*)&Pl[w][c * LDP + ch * 32 + g * 8];

    // PV: B-fragment = one vector read from Vt[d][k]
#pragma unroll
    for (int db = 0; db < 4; ++db) {
#pragma unroll
      for (int ch = 0; ch < 2; ++ch) {
        bf16x8 bv = *(const bf16x8*)&Vt[cur][(db * 16 + c) * LDVT + ch * 32 + g * 8];
        o[db] = mfma16(pa[ch], bv, o[db]);
      }
    }
  }

  int b_ = bh >> 4, hh = bh & 15;
#pragma unroll
  for (int r = 0; r < 4; ++r) {
    float inv = 1.0f / lrun[r];
#pragma unroll
    for (int db = 0; db < 4; ++db)
      ctx[(size_t)(b_ * T_ + qbase + g * 4 + r) * C_ + hh * D_ + db * 16 + c] =
          __float2bfloat16(o[db][r] * inv);
  }
}

extern "C" void kernel_launch(void* const* d_in, const int* in_sizes, int n_in, void* d_out,
                              int out_size, void* d_ws, size_t ws_size, hipStream_t stream) {
  const float* x = (const float*)d_in[0];
  const float* anw = (const float*)d_in[2];
  const float* mnw = (const float*)d_in[3];
  const float* q_w = (const float*)d_in[4];
  const float* q_b = (const float*)d_in[5];
  const float* k_w = (const float*)d_in[6];
  const float* k_b = (const float*)d_in[7];
  const float* v_w = (const float*)d_in[8];
  const float* v_b = (const float*)d_in[9];
  const float* o_w = (const float*)d_in[10];
  const float* o_b = (const float*)d_in[11];
  const float* w1 = (const float*)d_in[12];
  const float* b1 = (const float*)d_in[13];
  const float* w2 = (const float*)d_in[14];
  const float* b2 = (const float*)d_in[15];
  float* out = (float*)d_out;
  char* ws = (char*)d_ws;

  // ws layout (80 MB total, with reuse)
  bf16* qkvT = (bf16*)(ws + 0);         // 6 MB  [3072][1024]
  bf16* owT = (bf16*)(ws + 6291456);    // 2 MB
  bf16* w1T = (bf16*)(ws + 8388608);    // 8 MB
  bf16* w2T = (bf16*)(ws + 16777216);   // 8 MB
  bf16* h = (bf16*)(ws + 25165824);     // 8 MB
  bf16* qb = (bf16*)(ws + 33554432);    // 8 MB (qkv bf16 base; k,v follow)
  bf16* ctx = (bf16*)(ws + 58720256);   // 8 MB
  float* x2 = (float*)(ws + 67108864);  // 16 MB
  bf16* m = h;                          // reuse
  bf16* hid = qb;                       // reuse qb..ctx (32 MB) after attention
  float* qkvb = (float*)(ws + 67108864);  // overlaps x2 (dead until o-proj)
  bf16* kb = qb + 4194304;
  bf16* vb = qb + 8388608;

  cvt_transpose<<<dim3(32, 32), 256, 0, stream>>>(q_w, qkvT, 1024, 1024);
  cvt_transpose<<<dim3(32, 32), 256, 0, stream>>>(k_w, qkvT + 1048576, 1024, 1024);
  cvt_transpose<<<dim3(32, 32), 256, 0, stream>>>(v_w, qkvT + 2097152, 1024, 1024);
  cvt_transpose<<<dim3(32, 32), 256, 0, stream>>>(o_w, owT, 1024, 1024);
  cvt_transpose<<<dim3(128, 32), 256, 0, stream>>>(w1, w1T, 1024, 4096);
  cvt_transpose<<<dim3(32, 128), 256, 0, stream>>>(w2, w2T, 4096, 1024);
  pack_bias<<<12, 256, 0, stream>>>(q_b, k_b, v_b, qkvb);

  rmsnorm_kernel<<<4096, 256, 0, stream>>>(x, anw, h);

  // fused QKV: C[4096][3072]
  gemm_kernel<0><<<dim3(24, 32), 256, 0, stream>>>(h, qkvT, qkvb, qb, out, nullptr, 4096, 3072, 1024);

  attn_kernel<<<dim3(32, 32), 256, 0, stream>>>(qb, kb, vb, ctx);

  gemm_kernel<1><<<dim3(8, 32), 256, 0, stream>>>(ctx, owT, o_b, nullptr, x2, x, 4096, 1024, 1024);

  rmsnorm_kernel<<<4096, 256, 0, stream>>>(x2, mnw, m);

  gemm_kernel<2><<<dim3(32, 32), 256, 0, stream>>>(m, w1T, b1, hid, nullptr, nullptr, 4096, 4096, 1024);
  gemm_kernel<1><<<dim3(8, 32), 256, 0, stream>>>(hid, w2T, b2, nullptr, out, x2, 4096, 1024, 4096);
}

// Round 3
// 422.458 us; speedup vs baseline: 1.8062x; 1.0118x over previous
//
#include <hip/hip_runtime.h>
#include <hip/hip_bf16.h>

// Transformer block fwd (B=2,T=2048,C=1024,H=16,D=64,HID=4096), bf16 MFMA compute.
// Round 3: barrier-free flash attention (V pre-transposed in global, K/V frags from L2,
//          no KV-loop __syncthreads), LPT block order. GEMMs unchanged (m97 structure).

#define B_ 2
#define T_ 2048
#define C_ 1024
#define H_ 16
#define D_ 64
#define HID_ 4096
#define M_ 4096  // B*T

typedef __bf16 bf16x8 __attribute__((ext_vector_type(8)));
typedef unsigned short ushort8 __attribute__((ext_vector_type(8)));
typedef float f32x4 __attribute__((ext_vector_type(4)));
using bf16 = __hip_bfloat16;

static __device__ __forceinline__ f32x4 mfma16(bf16x8 a, bf16x8 b, f32x4 c) {
  return __builtin_amdgcn_mfma_f32_16x16x32_bf16(a, b, c, 0, 0, 0);
}

// async global->LDS, 16B per lane; LDS dest = wave-uniform base + lane*16
static __device__ __forceinline__ void gload16(const bf16* g, bf16* l) {
  __builtin_amdgcn_global_load_lds(
      (const __attribute__((address_space(1))) unsigned int*)g,
      (__attribute__((address_space(3))) unsigned int*)l, 16, 0, 0);
}

// ---- weight convert + transpose: in f32 [K][N] -> out bf16 [N][K] ----
__global__ __launch_bounds__(256) void cvt_transpose(const float* __restrict__ in,
                                                     bf16* __restrict__ out, int K, int N) {
  __shared__ float tile[32][33];
  int tid = threadIdx.x, tx = tid & 31, ty = tid >> 5;
  int n0 = blockIdx.x * 32, k0 = blockIdx.y * 32;
#pragma unroll
  for (int i = 0; i < 4; ++i) {
    int r = ty + i * 8;
    tile[r][tx] = in[(size_t)(k0 + r) * N + n0 + tx];
  }
  __syncthreads();
#pragma unroll
  for (int i = 0; i < 4; ++i) {
    int r = ty + i * 8;
    out[(size_t)(n0 + r) * K + k0 + tx] = __float2bfloat16(tile[tx][r]);
  }
}

// ---- bf16 transpose per head: in (B,H,T,D) -> out (B,H,D,T) ----
__global__ __launch_bounds__(256) void transpose_vt(const bf16* __restrict__ in,
                                                    bf16* __restrict__ out) {
  __shared__ bf16 tile[32][33];
  int tid = threadIdx.x, tx = tid & 31, ty = tid >> 5;
  int d0 = blockIdx.x * 32, t0 = blockIdx.y * 32, bh = blockIdx.z;
  const bf16* ih = in + (size_t)bh * T_ * D_;
  bf16* oh = out + (size_t)bh * T_ * D_;
#pragma unroll
  for (int i = 0; i < 4; ++i) {
    int r = ty + i * 8;
    tile[r][tx] = ih[(size_t)(t0 + r) * D_ + d0 + tx];
  }
  __syncthreads();
#pragma unroll
  for (int i = 0; i < 4; ++i) {
    int r = ty + i * 8;
    oh[(size_t)(d0 + r) * T_ + t0 + tx] = tile[tx][r];
  }
}

// ---- pack q/k/v bias into one 3072 vector ----
__global__ __launch_bounds__(256) void pack_bias(const float* __restrict__ q,
                                                 const float* __restrict__ k,
                                                 const float* __restrict__ v,
                                                 float* __restrict__ o) {
  int i = blockIdx.x * 256 + threadIdx.x;
  o[i] = i < 1024 ? q[i] : (i < 2048 ? k[i - 1024] : v[i - 2048]);
}

// ---- RMSNorm: x f32 [rows][1024] -> out bf16 ----
__global__ __launch_bounds__(256) void rmsnorm_kernel(const float* __restrict__ x,
                                                      const float* __restrict__ w,
                                                      bf16* __restrict__ out) {
  int row = blockIdx.x, tid = threadIdx.x;
  float4 v = ((const float4*)(x + (size_t)row * C_))[tid];
  float ss = v.x * v.x + v.y * v.y + v.z * v.z + v.w * v.w;
#pragma unroll
  for (int d = 1; d < 64; d <<= 1) ss += __shfl_xor(ss, d);
  __shared__ float wsum[4];
  if ((tid & 63) == 0) wsum[tid >> 6] = ss;
  __syncthreads();
  float tot = wsum[0] + wsum[1] + wsum[2] + wsum[3];
  float r = rsqrtf(tot * (1.0f / C_) + 1e-5f);
  float4 wv = ((const float4*)w)[tid];
  bf16* o = out + (size_t)row * C_ + tid * 4;
  o[0] = __float2bfloat16(v.x * wv.x * r);
  o[1] = __float2bfloat16(v.y * wv.y * r);
  o[2] = __float2bfloat16(v.z * wv.z * r);
  o[3] = __float2bfloat16(v.w * wv.w * r);
}

// ---- GEMM: C[M,N] = A[M,K] @ Bt[N,K]^T + bias. 128x128 tile, BK=64, 4 waves.
// m97 structure: linear LDS [128][64], global_load_lds width-16 staging.
// EPI 0: fused-QKV scatter (bf16 (B,H,T,D) x3; f32 dup for k,v)
// EPI 1: f32 out = acc + bias + res
// EPI 2: bf16 out = gelu(acc + bias)
template <int EPI>
__global__ __launch_bounds__(256) void gemm_kernel(
    const bf16* __restrict__ A, const bf16* __restrict__ Bt, const float* __restrict__ bias,
    bf16* __restrict__ bfout, float* __restrict__ fout, const float* __restrict__ res,
    int M, int N, int K) {
  __shared__ bf16 Al[128 * 64];
  __shared__ bf16 Bl[128 * 64];
  int tid = threadIdx.x, w = tid >> 6, l = tid & 63;
  int g = l >> 4, c = l & 15;
  int m0 = blockIdx.y * 128, n0 = blockIdx.x * 128;
  int wm = (w >> 1) * 64, wn = (w & 1) * 64;
  int KT = K >> 6;
  int lrow = l >> 3, lcol = (l & 7) * 8;

  const bf16* gA = A + (size_t)(m0 + w * 32 + lrow) * K + lcol;
  const bf16* gB = Bt + (size_t)(n0 + w * 32 + lrow) * K + lcol;

  f32x4 acc[4][4] = {};
  for (int kt = 0; kt < KT; ++kt) {
#pragma unroll
    for (int i = 0; i < 4; ++i) {
      gload16(gA + (size_t)i * 8 * K + kt * 64, Al + (w * 4 + i) * 512);
      gload16(gB + (size_t)i * 8 * K + kt * 64, Bl + (w * 4 + i) * 512);
    }
    __syncthreads();
#pragma unroll
    for (int ch = 0; ch < 2; ++ch) {
      bf16x8 af[4], bfr[4];
#pragma unroll
      for (int f = 0; f < 4; ++f)
        af[f] = *(const bf16x8*)&Al[(wm + f * 16 + c) * 64 + ch * 32 + g * 8];
#pragma unroll
      for (int f = 0; f < 4; ++f)
        bfr[f] = *(const bf16x8*)&Bl[(wn + f * 16 + c) * 64 + ch * 32 + g * 8];
#pragma unroll
      for (int mf = 0; mf < 4; ++mf)
#pragma unroll
        for (int nf = 0; nf < 4; ++nf) acc[mf][nf] = mfma16(af[mf], bfr[nf], acc[mf][nf]);
    }
    __syncthreads();
  }

#pragma unroll
  for (int mf = 0; mf < 4; ++mf) {
#pragma unroll
    for (int nf = 0; nf < 4; ++nf) {
      int gn = n0 + wn + nf * 16 + c;
      float bv = bias[gn];
#pragma unroll
      for (int r = 0; r < 4; ++r) {
        int gm = m0 + wm + mf * 16 + g * 4 + r;
        float v = acc[mf][nf][r] + bv;
        if (EPI == 0) {
          int part = gn >> 10, wi = gn & 1023, hh = wi >> 6, d = wi & 63;
          int b_ = gm >> 11, t = gm & 2047;
          size_t idx = ((size_t)(b_ * H_ + hh) * T_ + t) * D_ + d;
          bfout[(size_t)part * 4194304 + idx] = __float2bfloat16(v);
          if (part) fout[(size_t)part * 4194304 + idx] = v;
        } else if (EPI == 1) {
          size_t idx = (size_t)gm * N + gn;
          fout[idx] = v + res[idx];
        } else {
          size_t idx = (size_t)gm * N + gn;
          float gl = 0.5f * v * (1.0f + erff(v * 0.70710678118f));
          bfout[idx] = __float2bfloat16(gl);
        }
      }
    }
  }
}

// ---- Flash attention (causal), barrier-free: Q,K bf16 (B,H,T,D), Vt bf16 (B,H,D,T).
// K and V^T fragments read straight from global (L2-resident per head). Only P does a
// same-wave LDS round-trip (no __syncthreads anywhere in the KV loop).
__global__ __launch_bounds__(256) void attn_kernel(const bf16* __restrict__ Q,
                                                   const bf16* __restrict__ Kb,
                                                   const bf16* __restrict__ Vt,
                                                   bf16* __restrict__ ctx) {
  constexpr int LDP = 80;  // row 160B: write banks g*8 + c/2 -> 2-way (free)
  __shared__ bf16 Pl[4][16 * LDP];
  int tid = threadIdx.x, w = tid >> 6, l = tid & 63, g = l >> 4, c = l & 15;
  int bid = blockIdx.x;
  int qt = 31 - (bid >> 5);  // LPT: heavy (large qt) blocks first
  int bh = bid & 31;         // same-bh blocks stride 32 -> same XCD -> K/V L2 locality
  int qbase = qt * 64 + w * 16;
  const bf16* Qh = Q + (size_t)bh * T_ * D_;
  const bf16* Kh = Kb + (size_t)bh * T_ * D_;
  const bf16* Vh = Vt + (size_t)bh * T_ * D_;  // [D][T]

  bf16x8 aq[2];
#pragma unroll
  for (int ch = 0; ch < 2; ++ch)
    aq[ch] = *(const bf16x8*)&Qh[(size_t)(qbase + c) * D_ + ch * 32 + g * 8];

  f32x4 o[4] = {};
  float mrun[4], lrun[4];
#pragma unroll
  for (int r = 0; r < 4; ++r) { mrun[r] = -1e30f; lrun[r] = 0.f; }

  for (int kt = 0; kt <= qt; ++kt) {
    int kv0 = kt * 64;

    // S = Q K^T * scale (K B-frags: 16B global loads, L2-hot)
    f32x4 sf[4];
#pragma unroll
    for (int kb = 0; kb < 4; ++kb) {
      bf16x8 bk0 = *(const bf16x8*)&Kh[(size_t)(kv0 + kb * 16 + c) * D_ + g * 8];
      bf16x8 bk1 = *(const bf16x8*)&Kh[(size_t)(kv0 + kb * 16 + c) * D_ + 32 + g * 8];
      f32x4 t = {};
      t = mfma16(aq[0], bk0, t);
      t = mfma16(aq[1], bk1, t);
      sf[kb] = t;
    }
    float s[4][4];
#pragma unroll
    for (int kb = 0; kb < 4; ++kb)
#pragma unroll
      for (int r = 0; r < 4; ++r) s[kb][r] = sf[kb][r] * 0.125f;
    if (kt == qt) {
#pragma unroll
      for (int kb = 0; kb < 4; ++kb)
#pragma unroll
        for (int r = 0; r < 4; ++r) {
          int qi = qbase + g * 4 + r;
          int kv = kv0 + kb * 16 + c;
          if (kv > qi) s[kb][r] = -1e30f;
        }
    }
    // online softmax (row q = g*4+r lives on the 16 lanes sharing g)
    float mnew[4], alpha[4];
#pragma unroll
    for (int r = 0; r < 4; ++r) {
      float tm = fmaxf(fmaxf(s[0][r], s[1][r]), fmaxf(s[2][r], s[3][r]));
#pragma unroll
      for (int d = 1; d < 16; d <<= 1) tm = fmaxf(tm, __shfl_xor(tm, d));
      mnew[r] = fmaxf(mrun[r], tm);
      alpha[r] = __expf(mrun[r] - mnew[r]);
      mrun[r] = mnew[r];
    }
#pragma unroll
    for (int r = 0; r < 4; ++r) {
      float asum = 0.f;
#pragma unroll
      for (int kb = 0; kb < 4; ++kb) {
        float p = __expf(s[kb][r] - mnew[r]);
        s[kb][r] = p;
        asum += p;
      }
#pragma unroll
      for (int d = 1; d < 16; d <<= 1) asum += __shfl_xor(asum, d);
      lrun[r] = lrun[r] * alpha[r] + asum;
    }
#pragma unroll
    for (int db = 0; db < 4; ++db)
#pragma unroll
      for (int r = 0; r < 4; ++r) o[db][r] *= alpha[r];

    // P (C-layout) -> per-wave LDS -> A-fragment layout (same wave, no barrier)
#pragma unroll
    for (int kb = 0; kb < 4; ++kb)
#pragma unroll
      for (int r = 0; r < 4; ++r)
        Pl[w][(g * 4 + r) * LDP + kb * 16 + c] = __float2bfloat16(s[kb][r]);
    bf16x8 pa[2];
#pragma unroll
    for (int ch = 0; ch < 2; ++ch)
      pa[ch] = *(const bf16x8*)&Pl[w][c * LDP + ch * 32 + g * 8];

    // PV: B-frag = 16B global load from V^T[d][t] (L2-hot)
#pragma unroll
    for (int db = 0; db < 4; ++db) {
#pragma unroll
      for (int ch = 0; ch < 2; ++ch) {
        bf16x8 bv = *(const bf16x8*)&Vh[(size_t)(db * 16 + c) * T_ + kv0 + ch * 32 + g * 8];
        o[db] = mfma16(pa[ch], bv, o[db]);
      }
    }
  }

  int b_ = bh >> 4, hh = bh & 15;
#pragma unroll
  for (int r = 0; r < 4; ++r) {
    float inv = 1.0f / lrun[r];
#pragma unroll
    for (int db = 0; db < 4; ++db)
      ctx[(size_t)(b_ * T_ + qbase + g * 4 + r) * C_ + hh * D_ + db * 16 + c] =
          __float2bfloat16(o[db][r] * inv);
  }
}

extern "C" void kernel_launch(void* const* d_in, const int* in_sizes, int n_in, void* d_out,
                              int out_size, void* d_ws, size_t ws_size, hipStream_t stream) {
  const float* x = (const float*)d_in[0];
  const float* anw = (const float*)d_in[2];
  const float* mnw = (const float*)d_in[3];
  const float* q_w = (const float*)d_in[4];
  const float* q_b = (const float*)d_in[5];
  const float* k_w = (const float*)d_in[6];
  const float* k_b = (const float*)d_in[7];
  const float* v_w = (const float*)d_in[8];
  const float* v_b = (const float*)d_in[9];
  const float* o_w = (const float*)d_in[10];
  const float* o_b = (const float*)d_in[11];
  const float* w1 = (const float*)d_in[12];
  const float* b1 = (const float*)d_in[13];
  const float* w2 = (const float*)d_in[14];
  const float* b2 = (const float*)d_in[15];
  float* out = (float*)d_out;
  char* ws = (char*)d_ws;

  // ws layout (80 MB, reused):
  bf16* qkvT = (bf16*)(ws + 0);          // 6 MB [3072][1024]
  bf16* owT = (bf16*)(ws + 6291456);     // 2 MB
  bf16* w1T = (bf16*)(ws + 8388608);     // 8 MB
  bf16* w2T = (bf16*)(ws + 16777216);    // 8 MB
  bf16* h = (bf16*)(ws + 25165824);      // 8 MB  (also m)
  bf16* qb = (bf16*)(ws + 33554432);     // 8 MB  (qkv bf16; k,v follow)
  bf16* kb = (bf16*)(ws + 41943040);     // 8 MB
  bf16* vb = (bf16*)(ws + 50331648);     // 8 MB
  bf16* vtb = (bf16*)(ws + 58720256);    // 8 MB  V^T (B,H,D,T)
  bf16* ctx = (bf16*)(ws + 67108864);    // 8 MB
  float* x2 = (float*)(ws + 33554432);   // 16 MB over qb+kb (dead after attention)
  bf16* m = h;                           // reuse
  bf16* hid = vb;                        // 32 MB over vb,vtb,ctx (dead after o-proj)
  float* qkvb = (float*)(ws + 75497472); // 12 KB scratch tail (within 80 MB)

  cvt_transpose<<<dim3(32, 32), 256, 0, stream>>>(q_w, qkvT, 1024, 1024);
  cvt_transpose<<<dim3(32, 32), 256, 0, stream>>>(k_w, qkvT + 1048576, 1024, 1024);
  cvt_transpose<<<dim3(32, 32), 256, 0, stream>>>(v_w, qkvT + 2097152, 1024, 1024);
  cvt_transpose<<<dim3(32, 32), 256, 0, stream>>>(o_w, owT, 1024, 1024);
  cvt_transpose<<<dim3(128, 32), 256, 0, stream>>>(w1, w1T, 1024, 4096);
  cvt_transpose<<<dim3(32, 128), 256, 0, stream>>>(w2, w2T, 4096, 1024);
  pack_bias<<<12, 256, 0, stream>>>(q_b, k_b, v_b, qkvb);

  rmsnorm_kernel<<<4096, 256, 0, stream>>>(x, anw, h);

  // fused QKV: C[4096][3072]
  gemm_kernel<0><<<dim3(24, 32), 256, 0, stream>>>(h, qkvT, qkvb, qb, out, nullptr, 4096, 3072, 1024);

  transpose_vt<<<dim3(2, 64, 32), 256, 0, stream>>>(vb, vtb);

  attn_kernel<<<1024, 256, 0, stream>>>(qb, kb, vtb, ctx);

  gemm_kernel<1><<<dim3(8, 32), 256, 0, stream>>>(ctx, owT, o_b, nullptr, x2, x, 4096, 1024, 1024);

  rmsnorm_kernel<<<4096, 256, 0, stream>>>(x2, mnw, m);

  gemm_kernel<2><<<dim3(32, 32), 256, 0, stream>>>(m, w1T, b1, hid, nullptr, nullptr, 4096, 4096, 1024);
  gemm_kernel<1><<<dim3(8, 32), 256, 0, stream>>>(hid, w2T, b2, nullptr, out, x2, 4096, 1024, 4096);
}

// Round 4
// 413.507 us; speedup vs baseline: 1.8453x; 1.0216x over previous
//
#include <hip/hip_runtime.h>
#include <hip/hip_bf16.h>

// Transformer block fwd (B=2,T=2048,C=1024,H=16,D=64,HID=4096), bf16 MFMA compute.
// Round 4: attention with (256,2) launch bounds (registers for load ILP), paired KV
//          tiles (128/iter), V^T folded into QKV-GEMM epilogue. GEMMs m97 structure.

#define B_ 2
#define T_ 2048
#define C_ 1024
#define H_ 16
#define D_ 64
#define HID_ 4096
#define M_ 4096  // B*T

typedef __bf16 bf16x8 __attribute__((ext_vector_type(8)));
typedef float f32x4 __attribute__((ext_vector_type(4)));
using bf16 = __hip_bfloat16;

static __device__ __forceinline__ f32x4 mfma16(bf16x8 a, bf16x8 b, f32x4 c) {
  return __builtin_amdgcn_mfma_f32_16x16x32_bf16(a, b, c, 0, 0, 0);
}

// async global->LDS, 16B per lane; LDS dest = wave-uniform base + lane*16
static __device__ __forceinline__ void gload16(const bf16* g, bf16* l) {
  __builtin_amdgcn_global_load_lds(
      (const __attribute__((address_space(1))) unsigned int*)g,
      (__attribute__((address_space(3))) unsigned int*)l, 16, 0, 0);
}

// ---- weight convert + transpose: in f32 [K][N] -> out bf16 [N][K] ----
__global__ __launch_bounds__(256) void cvt_transpose(const float* __restrict__ in,
                                                     bf16* __restrict__ out, int K, int N) {
  __shared__ float tile[32][33];
  int tid = threadIdx.x, tx = tid & 31, ty = tid >> 5;
  int n0 = blockIdx.x * 32, k0 = blockIdx.y * 32;
#pragma unroll
  for (int i = 0; i < 4; ++i) {
    int r = ty + i * 8;
    tile[r][tx] = in[(size_t)(k0 + r) * N + n0 + tx];
  }
  __syncthreads();
#pragma unroll
  for (int i = 0; i < 4; ++i) {
    int r = ty + i * 8;
    out[(size_t)(n0 + r) * K + k0 + tx] = __float2bfloat16(tile[tx][r]);
  }
}

// ---- pack q/k/v bias into one 3072 vector ----
__global__ __launch_bounds__(256) void pack_bias(const float* __restrict__ q,
                                                 const float* __restrict__ k,
                                                 const float* __restrict__ v,
                                                 float* __restrict__ o) {
  int i = blockIdx.x * 256 + threadIdx.x;
  o[i] = i < 1024 ? q[i] : (i < 2048 ? k[i - 1024] : v[i - 2048]);
}

// ---- RMSNorm: x f32 [rows][1024] -> out bf16 ----
__global__ __launch_bounds__(256) void rmsnorm_kernel(const float* __restrict__ x,
                                                      const float* __restrict__ w,
                                                      bf16* __restrict__ out) {
  int row = blockIdx.x, tid = threadIdx.x;
  float4 v = ((const float4*)(x + (size_t)row * C_))[tid];
  float ss = v.x * v.x + v.y * v.y + v.z * v.z + v.w * v.w;
#pragma unroll
  for (int d = 1; d < 64; d <<= 1) ss += __shfl_xor(ss, d);
  __shared__ float wsum[4];
  if ((tid & 63) == 0) wsum[tid >> 6] = ss;
  __syncthreads();
  float tot = wsum[0] + wsum[1] + wsum[2] + wsum[3];
  float r = rsqrtf(tot * (1.0f / C_) + 1e-5f);
  float4 wv = ((const float4*)w)[tid];
  bf16* o = out + (size_t)row * C_ + tid * 4;
  o[0] = __float2bfloat16(v.x * wv.x * r);
  o[1] = __float2bfloat16(v.y * wv.y * r);
  o[2] = __float2bfloat16(v.z * wv.z * r);
  o[3] = __float2bfloat16(v.w * wv.w * r);
}

// ---- GEMM: C[M,N] = A[M,K] @ Bt[N,K]^T + bias. 128x128 tile, BK=64, 4 waves.
// EPI 0: fused-QKV scatter: q->bf16 (B,H,T,D); k->bf16 (B,H,T,D)+f32 dup;
//        v->bf16 V^T (B,H,D,T) + f32 dup in (B,H,T,D)
// EPI 1: f32 out = acc + bias + res
// EPI 2: bf16 out = gelu(acc + bias)
template <int EPI>
__global__ __launch_bounds__(256) void gemm_kernel(
    const bf16* __restrict__ A, const bf16* __restrict__ Bt, const float* __restrict__ bias,
    bf16* __restrict__ bfout, float* __restrict__ fout, const float* __restrict__ res,
    bf16* __restrict__ vtb, int M, int N, int K) {
  __shared__ bf16 Al[128 * 64];
  __shared__ bf16 Bl[128 * 64];
  int tid = threadIdx.x, w = tid >> 6, l = tid & 63;
  int g = l >> 4, c = l & 15;
  int m0 = blockIdx.y * 128, n0 = blockIdx.x * 128;
  int wm = (w >> 1) * 64, wn = (w & 1) * 64;
  int KT = K >> 6;
  int lrow = l >> 3, lcol = (l & 7) * 8;

  const bf16* gA = A + (size_t)(m0 + w * 32 + lrow) * K + lcol;
  const bf16* gB = Bt + (size_t)(n0 + w * 32 + lrow) * K + lcol;

  f32x4 acc[4][4] = {};
  for (int kt = 0; kt < KT; ++kt) {
#pragma unroll
    for (int i = 0; i < 4; ++i) {
      gload16(gA + (size_t)i * 8 * K + kt * 64, Al + (w * 4 + i) * 512);
      gload16(gB + (size_t)i * 8 * K + kt * 64, Bl + (w * 4 + i) * 512);
    }
    __syncthreads();
#pragma unroll
    for (int ch = 0; ch < 2; ++ch) {
      bf16x8 af[4], bfr[4];
#pragma unroll
      for (int f = 0; f < 4; ++f)
        af[f] = *(const bf16x8*)&Al[(wm + f * 16 + c) * 64 + ch * 32 + g * 8];
#pragma unroll
      for (int f = 0; f < 4; ++f)
        bfr[f] = *(const bf16x8*)&Bl[(wn + f * 16 + c) * 64 + ch * 32 + g * 8];
#pragma unroll
      for (int mf = 0; mf < 4; ++mf)
#pragma unroll
        for (int nf = 0; nf < 4; ++nf) acc[mf][nf] = mfma16(af[mf], bfr[nf], acc[mf][nf]);
    }
    __syncthreads();
  }

#pragma unroll
  for (int mf = 0; mf < 4; ++mf) {
#pragma unroll
    for (int nf = 0; nf < 4; ++nf) {
      int gn = n0 + wn + nf * 16 + c;
      float bv = bias[gn];
#pragma unroll
      for (int r = 0; r < 4; ++r) {
        int gm = m0 + wm + mf * 16 + g * 4 + r;
        float v = acc[mf][nf][r] + bv;
        if (EPI == 0) {
          int part = gn >> 10, wi = gn & 1023, hh = wi >> 6, d = wi & 63;
          int b_ = gm >> 11, t = gm & 2047;
          size_t idx = ((size_t)(b_ * H_ + hh) * T_ + t) * D_ + d;
          if (part == 2) {
            // v: bf16 transposed (B,H,D,T) + f32 dup
            vtb[((size_t)(b_ * H_ + hh) * D_ + d) * T_ + t] = __float2bfloat16(v);
            fout[(size_t)2 * 4194304 + idx] = v;
          } else {
            bfout[(size_t)part * 4194304 + idx] = __float2bfloat16(v);
            if (part) fout[(size_t)part * 4194304 + idx] = v;
          }
        } else if (EPI == 1) {
          size_t idx = (size_t)gm * N + gn;
          fout[idx] = v + res[idx];
        } else {
          size_t idx = (size_t)gm * N + gn;
          float gl = 0.5f * v * (1.0f + erff(v * 0.70710678118f));
          bfout[idx] = __float2bfloat16(gl);
        }
      }
    }
  }
}

// ---- Flash attention (causal), barrier-free, paired KV tiles (128 kv / iter).
// Q,K bf16 (B,H,T,D), Vt bf16 (B,H,D,T). K/V frags from global (L2-hot). Only P does a
// same-wave LDS round-trip. (256,2): VGPR budget 256 so all loads stay in flight.
__global__ __launch_bounds__(256, 2) void attn_kernel(const bf16* __restrict__ Q,
                                                      const bf16* __restrict__ Kb,
                                                      const bf16* __restrict__ Vt,
                                                      bf16* __restrict__ ctx) {
  constexpr int LDP = 136;  // row 272B: b128 reads uniform 8 lanes/quad; writes 4-way
  __shared__ bf16 Pl[4][16 * LDP];
  int tid = threadIdx.x, w = tid >> 6, l = tid & 63, g = l >> 4, c = l & 15;
  int bid = blockIdx.x;
  int qt = 31 - (bid >> 5);  // LPT: heavy blocks first
  int bh = bid & 31;         // same-bh stride 32 -> same XCD -> K/V L2 locality
  int qbase = qt * 64 + w * 16;
  const bf16* Qh = Q + (size_t)bh * T_ * D_;
  const bf16* Kh = Kb + (size_t)bh * T_ * D_;
  const bf16* Vh = Vt + (size_t)bh * T_ * D_;  // [D][T]

  bf16x8 aq[2];
#pragma unroll
  for (int ch = 0; ch < 2; ++ch)
    aq[ch] = *(const bf16x8*)&Qh[(size_t)(qbase + c) * D_ + ch * 32 + g * 8];

  f32x4 o[4] = {};
  float mrun[4], lrun[4];
#pragma unroll
  for (int r = 0; r < 4; ++r) { mrun[r] = -1e30f; lrun[r] = 0.f; }

  int NP = (qt >> 1) + 1;  // pairs of 64-tiles; overshoot past diagonal is masked
  for (int p = 0; p < NP; ++p) {
    int kv0 = p * 128;

    // QK^T over 8 kv-blocks of 16 (16 K loads; ILP across kb)
    f32x4 sf[8];
#pragma unroll
    for (int kb = 0; kb < 8; ++kb) {
      const bf16* kp = &Kh[(size_t)(kv0 + kb * 16 + c) * D_ + g * 8];
      bf16x8 bk0 = *(const bf16x8*)kp;
      bf16x8 bk1 = *(const bf16x8*)(kp + 32);
      f32x4 t = {};
      t = mfma16(aq[0], bk0, t);
      t = mfma16(aq[1], bk1, t);
      sf[kb] = t;
    }

    // V prefetch (independent of softmax; hides under it)
    bf16x8 bv[4][4];
#pragma unroll
    for (int db = 0; db < 4; ++db)
#pragma unroll
      for (int ck = 0; ck < 4; ++ck)
        bv[db][ck] = *(const bf16x8*)&Vh[(size_t)(db * 16 + c) * T_ + kv0 + ck * 32 + g * 8];

    float s[8][4];
#pragma unroll
    for (int kb = 0; kb < 8; ++kb)
#pragma unroll
      for (int r = 0; r < 4; ++r) s[kb][r] = sf[kb][r] * 0.125f;
    if (kv0 + 127 > qbase) {  // wave-uniform: only pairs straddling the diagonal
#pragma unroll
      for (int kb = 0; kb < 8; ++kb)
#pragma unroll
        for (int r = 0; r < 4; ++r) {
          int qi = qbase + g * 4 + r;
          int kv = kv0 + kb * 16 + c;
          if (kv > qi) s[kb][r] = -1e30f;
        }
    }
    // online softmax (row q = g*4+r lives on the 16 lanes sharing g)
    float mnew[4], alpha[4];
#pragma unroll
    for (int r = 0; r < 4; ++r) {
      float tm = s[0][r];
#pragma unroll
      for (int kb = 1; kb < 8; ++kb) tm = fmaxf(tm, s[kb][r]);
#pragma unroll
      for (int d = 1; d < 16; d <<= 1) tm = fmaxf(tm, __shfl_xor(tm, d));
      mnew[r] = fmaxf(mrun[r], tm);
      alpha[r] = __expf(mrun[r] - mnew[r]);
      mrun[r] = mnew[r];
    }
#pragma unroll
    for (int r = 0; r < 4; ++r) {
      float asum = 0.f;
#pragma unroll
      for (int kb = 0; kb < 8; ++kb) {
        float pv = __expf(s[kb][r] - mnew[r]);
        s[kb][r] = pv;
        asum += pv;
      }
#pragma unroll
      for (int d = 1; d < 16; d <<= 1) asum += __shfl_xor(asum, d);
      lrun[r] = lrun[r] * alpha[r] + asum;
    }
#pragma unroll
    for (int db = 0; db < 4; ++db)
#pragma unroll
      for (int r = 0; r < 4; ++r) o[db][r] *= alpha[r];

    // P (C-layout) -> per-wave LDS -> A-fragment layout (same wave, no barrier)
#pragma unroll
    for (int kb = 0; kb < 8; ++kb)
#pragma unroll
      for (int r = 0; r < 4; ++r)
        Pl[w][(g * 4 + r) * LDP + kb * 16 + c] = __float2bfloat16(s[kb][r]);
    bf16x8 pa[4];
#pragma unroll
    for (int ck = 0; ck < 4; ++ck)
      pa[ck] = *(const bf16x8*)&Pl[w][c * LDP + ck * 32 + g * 8];

    // PV: 16 MFMA, V frags already in registers
#pragma unroll
    for (int db = 0; db < 4; ++db)
#pragma unroll
      for (int ck = 0; ck < 4; ++ck) o[db] = mfma16(pa[ck], bv[db][ck], o[db]);
  }

  int b_ = bh >> 4, hh = bh & 15;
#pragma unroll
  for (int r = 0; r < 4; ++r) {
    float inv = 1.0f / lrun[r];
#pragma unroll
    for (int db = 0; db < 4; ++db)
      ctx[(size_t)(b_ * T_ + qbase + g * 4 + r) * C_ + hh * D_ + db * 16 + c] =
          __float2bfloat16(o[db][r] * inv);
  }
}

extern "C" void kernel_launch(void* const* d_in, const int* in_sizes, int n_in, void* d_out,
                              int out_size, void* d_ws, size_t ws_size, hipStream_t stream) {
  const float* x = (const float*)d_in[0];
  const float* anw = (const float*)d_in[2];
  const float* mnw = (const float*)d_in[3];
  const float* q_w = (const float*)d_in[4];
  const float* q_b = (const float*)d_in[5];
  const float* k_w = (const float*)d_in[6];
  const float* k_b = (const float*)d_in[7];
  const float* v_w = (const float*)d_in[8];
  const float* v_b = (const float*)d_in[9];
  const float* o_w = (const float*)d_in[10];
  const float* o_b = (const float*)d_in[11];
  const float* w1 = (const float*)d_in[12];
  const float* b1 = (const float*)d_in[13];
  const float* w2 = (const float*)d_in[14];
  const float* b2 = (const float*)d_in[15];
  float* out = (float*)d_out;
  char* ws = (char*)d_ws;

  // ws layout (80 MB, reused):
  bf16* qkvT = (bf16*)(ws + 0);          // 6 MB [3072][1024]
  bf16* owT = (bf16*)(ws + 6291456);     // 2 MB
  bf16* w1T = (bf16*)(ws + 8388608);     // 8 MB
  bf16* w2T = (bf16*)(ws + 16777216);    // 8 MB
  bf16* h = (bf16*)(ws + 25165824);      // 8 MB  (also m)
  bf16* qb = (bf16*)(ws + 33554432);     // 8 MB
  bf16* kb = (bf16*)(ws + 41943040);     // 8 MB
  bf16* vtb = (bf16*)(ws + 58720256);    // 8 MB  V^T (B,H,D,T), written by EPI0
  bf16* ctx = (bf16*)(ws + 67108864);    // 8 MB
  float* x2 = (float*)(ws + 33554432);   // 16 MB over qb+kb (dead after attention)
  bf16* m = h;                           // reuse
  bf16* hid = (bf16*)(ws + 50331648);    // 32 MB over vb-slot,vtb,ctx (dead after o-proj)
  float* qkvb = (float*)(ws + 75497472); // 12 KB scratch tail

  cvt_transpose<<<dim3(32, 32), 256, 0, stream>>>(q_w, qkvT, 1024, 1024);
  cvt_transpose<<<dim3(32, 32), 256, 0, stream>>>(k_w, qkvT + 1048576, 1024, 1024);
  cvt_transpose<<<dim3(32, 32), 256, 0, stream>>>(v_w, qkvT + 2097152, 1024, 1024);
  cvt_transpose<<<dim3(32, 32), 256, 0, stream>>>(o_w, owT, 1024, 1024);
  cvt_transpose<<<dim3(128, 32), 256, 0, stream>>>(w1, w1T, 1024, 4096);
  cvt_transpose<<<dim3(32, 128), 256, 0, stream>>>(w2, w2T, 4096, 1024);
  pack_bias<<<12, 256, 0, stream>>>(q_b, k_b, v_b, qkvb);

  rmsnorm_kernel<<<4096, 256, 0, stream>>>(x, anw, h);

  // fused QKV: C[4096][3072]; v written transposed for attention
  gemm_kernel<0><<<dim3(24, 32), 256, 0, stream>>>(h, qkvT, qkvb, qb, out, nullptr, vtb,
                                                   4096, 3072, 1024);

  attn_kernel<<<1024, 256, 0, stream>>>(qb, kb, vtb, ctx);

  gemm_kernel<1><<<dim3(8, 32), 256, 0, stream>>>(ctx, owT, o_b, nullptr, x2, x, nullptr,
                                                  4096, 1024, 1024);

  rmsnorm_kernel<<<4096, 256, 0, stream>>>(x2, mnw, m);

  gemm_kernel<2><<<dim3(32, 32), 256, 0, stream>>>(m, w1T, b1, hid, nullptr, nullptr, nullptr,
                                                   4096, 4096, 1024);
  gemm_kernel<1><<<dim3(8, 32), 256, 0, stream>>>(hid, w2T, b2, nullptr, out, x2, nullptr,
                                                  4096, 1024, 4096);
}

// Round 5
// 365.408 us; speedup vs baseline: 2.0882x; 1.1316x over previous
//
#include <hip/hip_runtime.h>
#include <hip/hip_bf16.h>

// Transformer block fwd (B=2,T=2048,C=1024,H=16,D=64,HID=4096), bf16 MFMA compute.
// Round 5: attention restructured to shared-LDS KV staging (m97-style 2-barrier tile
//          loop, global_load_lds + pre-swizzled source, 128-row q-tile / 4 waves).

#define B_ 2
#define T_ 2048
#define C_ 1024
#define H_ 16
#define D_ 64
#define HID_ 4096
#define M_ 4096  // B*T

typedef __bf16 bf16x8 __attribute__((ext_vector_type(8)));
typedef float f32x4 __attribute__((ext_vector_type(4)));
using bf16 = __hip_bfloat16;

static __device__ __forceinline__ f32x4 mfma16(bf16x8 a, bf16x8 b, f32x4 c) {
  return __builtin_amdgcn_mfma_f32_16x16x32_bf16(a, b, c, 0, 0, 0);
}

// async global->LDS, 16B per lane; LDS dest = wave-uniform base + lane*16
static __device__ __forceinline__ void gload16(const bf16* g, bf16* l) {
  __builtin_amdgcn_global_load_lds(
      (const __attribute__((address_space(1))) unsigned int*)g,
      (__attribute__((address_space(3))) unsigned int*)l, 16, 0, 0);
}

// ---- weight convert + transpose: in f32 [K][N] -> out bf16 [N][K] ----
__global__ __launch_bounds__(256) void cvt_transpose(const float* __restrict__ in,
                                                     bf16* __restrict__ out, int K, int N) {
  __shared__ float tile[32][33];
  int tid = threadIdx.x, tx = tid & 31, ty = tid >> 5;
  int n0 = blockIdx.x * 32, k0 = blockIdx.y * 32;
#pragma unroll
  for (int i = 0; i < 4; ++i) {
    int r = ty + i * 8;
    tile[r][tx] = in[(size_t)(k0 + r) * N + n0 + tx];
  }
  __syncthreads();
#pragma unroll
  for (int i = 0; i < 4; ++i) {
    int r = ty + i * 8;
    out[(size_t)(n0 + r) * K + k0 + tx] = __float2bfloat16(tile[tx][r]);
  }
}

// ---- pack q/k/v bias into one 3072 vector ----
__global__ __launch_bounds__(256) void pack_bias(const float* __restrict__ q,
                                                 const float* __restrict__ k,
                                                 const float* __restrict__ v,
                                                 float* __restrict__ o) {
  int i = blockIdx.x * 256 + threadIdx.x;
  o[i] = i < 1024 ? q[i] : (i < 2048 ? k[i - 1024] : v[i - 2048]);
}

// ---- RMSNorm: x f32 [rows][1024] -> out bf16 ----
__global__ __launch_bounds__(256) void rmsnorm_kernel(const float* __restrict__ x,
                                                      const float* __restrict__ w,
                                                      bf16* __restrict__ out) {
  int row = blockIdx.x, tid = threadIdx.x;
  float4 v = ((const float4*)(x + (size_t)row * C_))[tid];
  float ss = v.x * v.x + v.y * v.y + v.z * v.z + v.w * v.w;
#pragma unroll
  for (int d = 1; d < 64; d <<= 1) ss += __shfl_xor(ss, d);
  __shared__ float wsum[4];
  if ((tid & 63) == 0) wsum[tid >> 6] = ss;
  __syncthreads();
  float tot = wsum[0] + wsum[1] + wsum[2] + wsum[3];
  float r = rsqrtf(tot * (1.0f / C_) + 1e-5f);
  float4 wv = ((const float4*)w)[tid];
  bf16* o = out + (size_t)row * C_ + tid * 4;
  o[0] = __float2bfloat16(v.x * wv.x * r);
  o[1] = __float2bfloat16(v.y * wv.y * r);
  o[2] = __float2bfloat16(v.z * wv.z * r);
  o[3] = __float2bfloat16(v.w * wv.w * r);
}

// ---- GEMM: C[M,N] = A[M,K] @ Bt[N,K]^T + bias. 128x128 tile, BK=64, 4 waves.
// EPI 0: fused-QKV scatter: q->bf16 (B,H,T,D); k->bf16 (B,H,T,D)+f32 dup;
//        v->bf16 V^T (B,H,D,T) + f32 dup in (B,H,T,D)
// EPI 1: f32 out = acc + bias + res
// EPI 2: bf16 out = gelu(acc + bias)
template <int EPI>
__global__ __launch_bounds__(256) void gemm_kernel(
    const bf16* __restrict__ A, const bf16* __restrict__ Bt, const float* __restrict__ bias,
    bf16* __restrict__ bfout, float* __restrict__ fout, const float* __restrict__ res,
    bf16* __restrict__ vtb, int M, int N, int K) {
  __shared__ bf16 Al[128 * 64];
  __shared__ bf16 Bl[128 * 64];
  int tid = threadIdx.x, w = tid >> 6, l = tid & 63;
  int g = l >> 4, c = l & 15;
  int m0 = blockIdx.y * 128, n0 = blockIdx.x * 128;
  int wm = (w >> 1) * 64, wn = (w & 1) * 64;
  int KT = K >> 6;
  int lrow = l >> 3, lcol = (l & 7) * 8;

  const bf16* gA = A + (size_t)(m0 + w * 32 + lrow) * K + lcol;
  const bf16* gB = Bt + (size_t)(n0 + w * 32 + lrow) * K + lcol;

  f32x4 acc[4][4] = {};
  for (int kt = 0; kt < KT; ++kt) {
#pragma unroll
    for (int i = 0; i < 4; ++i) {
      gload16(gA + (size_t)i * 8 * K + kt * 64, Al + (w * 4 + i) * 512);
      gload16(gB + (size_t)i * 8 * K + kt * 64, Bl + (w * 4 + i) * 512);
    }
    __syncthreads();
#pragma unroll
    for (int ch = 0; ch < 2; ++ch) {
      bf16x8 af[4], bfr[4];
#pragma unroll
      for (int f = 0; f < 4; ++f)
        af[f] = *(const bf16x8*)&Al[(wm + f * 16 + c) * 64 + ch * 32 + g * 8];
#pragma unroll
      for (int f = 0; f < 4; ++f)
        bfr[f] = *(const bf16x8*)&Bl[(wn + f * 16 + c) * 64 + ch * 32 + g * 8];
#pragma unroll
      for (int mf = 0; mf < 4; ++mf)
#pragma unroll
        for (int nf = 0; nf < 4; ++nf) acc[mf][nf] = mfma16(af[mf], bfr[nf], acc[mf][nf]);
    }
    __syncthreads();
  }

#pragma unroll
  for (int mf = 0; mf < 4; ++mf) {
#pragma unroll
    for (int nf = 0; nf < 4; ++nf) {
      int gn = n0 + wn + nf * 16 + c;
      float bv = bias[gn];
#pragma unroll
      for (int r = 0; r < 4; ++r) {
        int gm = m0 + wm + mf * 16 + g * 4 + r;
        float v = acc[mf][nf][r] + bv;
        if (EPI == 0) {
          int part = gn >> 10, wi = gn & 1023, hh = wi >> 6, d = wi & 63;
          int b_ = gm >> 11, t = gm & 2047;
          size_t idx = ((size_t)(b_ * H_ + hh) * T_ + t) * D_ + d;
          if (part == 2) {
            vtb[((size_t)(b_ * H_ + hh) * D_ + d) * T_ + t] = __float2bfloat16(v);
            fout[(size_t)2 * 4194304 + idx] = v;
          } else {
            bfout[(size_t)part * 4194304 + idx] = __float2bfloat16(v);
            if (part) fout[(size_t)part * 4194304 + idx] = v;
          }
        } else if (EPI == 1) {
          size_t idx = (size_t)gm * N + gn;
          fout[idx] = v + res[idx];
        } else {
          size_t idx = (size_t)gm * N + gn;
          float gl = 0.5f * v * (1.0f + erff(v * 0.70710678118f));
          bfout[idx] = __float2bfloat16(gl);
        }
      }
    }
  }
}

// ---- Flash attention (causal): shared-LDS KV staging, 128-row q-tile, 4 waves.
// Q,K bf16 (B,H,T,D), Vt bf16 (B,H,D,T). Per 64-kv tile: stage K + V^T into LDS via
// global_load_lds (linear dest, source pre-swizzled so swizzled ds_read_b128 is
// 2-way-conflict-free), barrier, compute, barrier.
__global__ __launch_bounds__(256, 2) void attn_kernel(const bf16* __restrict__ Q,
                                                      const bf16* __restrict__ Kb,
                                                      const bf16* __restrict__ Vt,
                                                      bf16* __restrict__ ctx) {
  constexpr int LDP = 136;
  __shared__ bf16 Kl[64 * 64];
  __shared__ bf16 Vl[64 * 64];
  __shared__ bf16 Pl[4][16 * LDP];
  int tid = threadIdx.x, w = tid >> 6, l = tid & 63, g = l >> 4, c = l & 15;
  int bid = blockIdx.x;
  int qt = 15 - (bid >> 5);  // LPT: heavy q-tiles first
  int bh = bid & 31;         // same-bh stride 32 -> same XCD -> K/V L2 locality
  int qbase = qt * 128 + w * 32;
  const bf16* Qh = Q + (size_t)bh * T_ * D_;
  const bf16* Kh = Kb + (size_t)bh * T_ * D_;
  const bf16* Vh = Vt + (size_t)bh * T_ * D_;  // [D][T]

  // Q fragments: 32 rows/wave = 2 frags x 2 k-chunks
  bf16x8 aq[2][2];
#pragma unroll
  for (int qf = 0; qf < 2; ++qf)
#pragma unroll
    for (int ch = 0; ch < 2; ++ch)
      aq[qf][ch] = *(const bf16x8*)&Qh[(size_t)(qbase + qf * 16 + c) * D_ + ch * 32 + g * 8];

  f32x4 o[2][4] = {};
  float mrun[2][4], lrun[2][4];
#pragma unroll
  for (int qf = 0; qf < 2; ++qf)
#pragma unroll
    for (int r = 0; r < 4; ++r) { mrun[qf][r] = -1e30f; lrun[qf][r] = 0.f; }

  // staging geometry: lane -> lds row i*32+w*8+(l>>3), swizzled col chunk
  int srow = l >> 3;
  int sce = ((l & 7) * 8) ^ (srow << 3);  // pre-swizzled source elem col
  int cswz = (c & 7) << 3;                // read-side swizzle

  int NT = 2 * qt + 2;
  for (int ti = 0; ti < NT; ++ti) {
    int kv0 = ti * 64;
#pragma unroll
    for (int i = 0; i < 2; ++i) {
      int row = i * 32 + w * 8 + srow;
      gload16(&Kh[(size_t)(kv0 + row) * D_ + sce], Kl + i * 2048 + w * 512);
      gload16(&Vh[(size_t)row * T_ + kv0 + sce], Vl + i * 2048 + w * 512);
    }
    __syncthreads();  // drains vmcnt -> tiles ready

    // K fragments (shared across qf) and QK^T
    bf16x8 bk[4][2];
#pragma unroll
    for (int kb = 0; kb < 4; ++kb)
#pragma unroll
      for (int ch = 0; ch < 2; ++ch)
        bk[kb][ch] = *(const bf16x8*)&Kl[(kb * 16 + c) * 64 + ((ch * 32 + g * 8) ^ cswz)];
    f32x4 sf[2][4];
#pragma unroll
    for (int qf = 0; qf < 2; ++qf)
#pragma unroll
      for (int kb = 0; kb < 4; ++kb) {
        f32x4 t = {};
        t = mfma16(aq[qf][0], bk[kb][0], t);
        t = mfma16(aq[qf][1], bk[kb][1], t);
        sf[qf][kb] = t;
      }
    // V fragments (shared across qf)
    bf16x8 bvv[4][2];
#pragma unroll
    for (int db = 0; db < 4; ++db)
#pragma unroll
      for (int ck = 0; ck < 2; ++ck)
        bvv[db][ck] = *(const bf16x8*)&Vl[(db * 16 + c) * 64 + ((ck * 32 + g * 8) ^ cswz)];

    float s[2][4][4];
#pragma unroll
    for (int qf = 0; qf < 2; ++qf)
#pragma unroll
      for (int kb = 0; kb < 4; ++kb)
#pragma unroll
        for (int r = 0; r < 4; ++r) s[qf][kb][r] = sf[qf][kb][r] * 0.125f;
    if (kv0 + 63 > qbase) {  // wave-uniform; fully-masked tiles safe (exp->0)
#pragma unroll
      for (int qf = 0; qf < 2; ++qf)
#pragma unroll
        for (int kb = 0; kb < 4; ++kb)
#pragma unroll
          for (int r = 0; r < 4; ++r) {
            int qi = qbase + qf * 16 + g * 4 + r;
            int kv = kv0 + kb * 16 + c;
            if (kv > qi) s[qf][kb][r] = -1e30f;
          }
    }
    // online softmax (row = 16 lanes sharing g)
#pragma unroll
    for (int qf = 0; qf < 2; ++qf)
#pragma unroll
      for (int r = 0; r < 4; ++r) {
        float tm = fmaxf(fmaxf(s[qf][0][r], s[qf][1][r]), fmaxf(s[qf][2][r], s[qf][3][r]));
#pragma unroll
        for (int d = 1; d < 16; d <<= 1) tm = fmaxf(tm, __shfl_xor(tm, d));
        float mn = fmaxf(mrun[qf][r], tm);
        float al = __expf(mrun[qf][r] - mn);
        mrun[qf][r] = mn;
        float asum = 0.f;
#pragma unroll
        for (int kb = 0; kb < 4; ++kb) {
          float pv = __expf(s[qf][kb][r] - mn);
          s[qf][kb][r] = pv;
          asum += pv;
        }
#pragma unroll
        for (int d = 1; d < 16; d <<= 1) asum += __shfl_xor(asum, d);
        lrun[qf][r] = lrun[qf][r] * al + asum;
#pragma unroll
        for (int db = 0; db < 4; ++db) o[qf][db][r] *= al;
      }

    // P (C-layout) -> per-wave LDS -> A-frag layout; PV
#pragma unroll
    for (int qf = 0; qf < 2; ++qf) {
#pragma unroll
      for (int kb = 0; kb < 4; ++kb)
#pragma unroll
        for (int r = 0; r < 4; ++r)
          Pl[w][(g * 4 + r) * LDP + kb * 16 + c] = __float2bfloat16(s[qf][kb][r]);
      bf16x8 pa0 = *(const bf16x8*)&Pl[w][c * LDP + g * 8];
      bf16x8 pa1 = *(const bf16x8*)&Pl[w][c * LDP + 32 + g * 8];
#pragma unroll
      for (int db = 0; db < 4; ++db) {
        o[qf][db] = mfma16(pa0, bvv[db][0], o[qf][db]);
        o[qf][db] = mfma16(pa1, bvv[db][1], o[qf][db]);
      }
    }
    __syncthreads();  // all waves done reading before next stage
  }

  int b_ = bh >> 4, hh = bh & 15;
#pragma unroll
  for (int qf = 0; qf < 2; ++qf)
#pragma unroll
    for (int r = 0; r < 4; ++r) {
      float inv = 1.0f / lrun[qf][r];
#pragma unroll
      for (int db = 0; db < 4; ++db)
        ctx[(size_t)(b_ * T_ + qbase + qf * 16 + g * 4 + r) * C_ + hh * D_ + db * 16 + c] =
            __float2bfloat16(o[qf][db][r] * inv);
    }
}

extern "C" void kernel_launch(void* const* d_in, const int* in_sizes, int n_in, void* d_out,
                              int out_size, void* d_ws, size_t ws_size, hipStream_t stream) {
  const float* x = (const float*)d_in[0];
  const float* anw = (const float*)d_in[2];
  const float* mnw = (const float*)d_in[3];
  const float* q_w = (const float*)d_in[4];
  const float* q_b = (const float*)d_in[5];
  const float* k_w = (const float*)d_in[6];
  const float* k_b = (const float*)d_in[7];
  const float* v_w = (const float*)d_in[8];
  const float* v_b = (const float*)d_in[9];
  const float* o_w = (const float*)d_in[10];
  const float* o_b = (const float*)d_in[11];
  const float* w1 = (const float*)d_in[12];
  const float* b1 = (const float*)d_in[13];
  const float* w2 = (const float*)d_in[14];
  const float* b2 = (const float*)d_in[15];
  float* out = (float*)d_out;
  char* ws = (char*)d_ws;

  // ws layout (80 MB, reused):
  bf16* qkvT = (bf16*)(ws + 0);          // 6 MB [3072][1024]
  bf16* owT = (bf16*)(ws + 6291456);     // 2 MB
  bf16* w1T = (bf16*)(ws + 8388608);     // 8 MB
  bf16* w2T = (bf16*)(ws + 16777216);    // 8 MB
  bf16* h = (bf16*)(ws + 25165824);      // 8 MB  (also m)
  bf16* qb = (bf16*)(ws + 33554432);     // 8 MB
  bf16* kb = (bf16*)(ws + 41943040);     // 8 MB
  bf16* vtb = (bf16*)(ws + 58720256);    // 8 MB  V^T (B,H,D,T), written by EPI0
  bf16* ctx = (bf16*)(ws + 67108864);    // 8 MB
  float* x2 = (float*)(ws + 33554432);   // 16 MB over qb+kb (dead after attention)
  bf16* m = h;                           // reuse
  bf16* hid = (bf16*)(ws + 50331648);    // 32 MB over vb-slot,vtb,ctx (dead after o-proj)
  float* qkvb = (float*)(ws + 75497472); // 12 KB scratch tail

  cvt_transpose<<<dim3(32, 32), 256, 0, stream>>>(q_w, qkvT, 1024, 1024);
  cvt_transpose<<<dim3(32, 32), 256, 0, stream>>>(k_w, qkvT + 1048576, 1024, 1024);
  cvt_transpose<<<dim3(32, 32), 256, 0, stream>>>(v_w, qkvT + 2097152, 1024, 1024);
  cvt_transpose<<<dim3(32, 32), 256, 0, stream>>>(o_w, owT, 1024, 1024);
  cvt_transpose<<<dim3(128, 32), 256, 0, stream>>>(w1, w1T, 1024, 4096);
  cvt_transpose<<<dim3(32, 128), 256, 0, stream>>>(w2, w2T, 4096, 1024);
  pack_bias<<<12, 256, 0, stream>>>(q_b, k_b, v_b, qkvb);

  rmsnorm_kernel<<<4096, 256, 0, stream>>>(x, anw, h);

  // fused QKV: C[4096][3072]; v written transposed for attention
  gemm_kernel<0><<<dim3(24, 32), 256, 0, stream>>>(h, qkvT, qkvb, qb, out, nullptr, vtb,
                                                   4096, 3072, 1024);

  attn_kernel<<<512, 256, 0, stream>>>(qb, kb, vtb, ctx);

  gemm_kernel<1><<<dim3(8, 32), 256, 0, stream>>>(ctx, owT, o_b, nullptr, x2, x, nullptr,
                                                  4096, 1024, 1024);

  rmsnorm_kernel<<<4096, 256, 0, stream>>>(x2, mnw, m);

  gemm_kernel<2><<<dim3(32, 32), 256, 0, stream>>>(m, w1T, b1, hid, nullptr, nullptr, nullptr,
                                                   4096, 4096, 1024);
  gemm_kernel<1><<<dim3(8, 32), 256, 0, stream>>>(hid, w2T, b2, nullptr, out, x2, nullptr,
                                                  4096, 1024, 4096);
}